// Round 2
// baseline (698.588 us; speedup 1.0000x reference)
//
#include <hip/hip_runtime.h>

// DotAttention: B=32, S=4096, D=1024, fp32.
// scores[b,s] = ctx[b,:]·inp[b,s,:]; masked softmax over s; out[b,:] = sum_s attn*inp[b,s,:]
// One-pass online softmax, fused: read inputs (512 MB) exactly once.

constexpr float kNegInf = -1e30f;
constexpr int kB = 32, kS = 4096, kD = 1024;
constexpr int kD4 = kD / 4;   // 256 float4 per row
constexpr int kV4 = kD4 / 64; // 4 float4 per lane

// Pass 1: one wave per (b, s-chunk). Streams `rows` contiguous rows once,
// maintains online-softmax state (m, l) + acc[1024] distributed over 64 lanes.
__global__ __launch_bounds__(64) void
dotattn_pass1(const float* __restrict__ ctx, const float* __restrict__ inp,
              const int* __restrict__ mask, float* __restrict__ pacc,
              float* __restrict__ pm, float* __restrict__ pl,
              int np, int rows)
{
    const int blk  = blockIdx.x;       // 0 .. kB*np-1
    const int b    = blk / np;
    const int chnk = blk % np;
    const int lane = threadIdx.x;      // 0..63 (one wave per block)

    // Context fragment: lane holds d = 4*(lane + 64*k), k=0..3
    const float4* ctx4 = reinterpret_cast<const float4*>(ctx) + (size_t)b * kD4;
    float4 c[kV4];
#pragma unroll
    for (int k = 0; k < kV4; ++k) c[k] = ctx4[lane + 64 * k];

    float m = kNegInf, l = 0.f;
    float4 acc[kV4];
#pragma unroll
    for (int k = 0; k < kV4; ++k) acc[k] = make_float4(0.f, 0.f, 0.f, 0.f);

    const int s0 = chnk * rows;
    const float4* base4 = reinterpret_cast<const float4*>(inp) + (size_t)b * kS * kD4;
    const int* mrow = mask + (size_t)b * kS;

    for (int r = 0; r < rows; ++r) {
        const int s = s0 + r;
        const float4* row4 = base4 + (size_t)s * kD4;
        float4 x[kV4];
#pragma unroll
        for (int k = 0; k < kV4; ++k) x[k] = row4[lane + 64 * k];

        // dot(context, row) — 16 FMAs per lane, then 64-lane butterfly reduce
        float p = 0.f;
#pragma unroll
        for (int k = 0; k < kV4; ++k) {
            p = fmaf(c[k].x, x[k].x, p);
            p = fmaf(c[k].y, x[k].y, p);
            p = fmaf(c[k].z, x[k].z, p);
            p = fmaf(c[k].w, x[k].w, p);
        }
#pragma unroll
        for (int off = 32; off > 0; off >>= 1) p += __shfl_xor(p, off, 64);

        const float score = (mrow[s] != 0) ? p : kNegInf;

        // online softmax update (matches jnp semantics incl. all-masked case)
        const float mnew  = fmaxf(m, score);
        const float scale = __expf(m - mnew);      // exp(0)=1 or decay old state
        const float w     = __expf(score - mnew);
        l = l * scale + w;
#pragma unroll
        for (int k = 0; k < kV4; ++k) {
            acc[k].x = fmaf(w, x[k].x, acc[k].x * scale);
            acc[k].y = fmaf(w, x[k].y, acc[k].y * scale);
            acc[k].z = fmaf(w, x[k].z, acc[k].z * scale);
            acc[k].w = fmaf(w, x[k].w, acc[k].w * scale);
        }
        m = mnew;
    }

    float4* pacc4 = reinterpret_cast<float4*>(pacc) + (size_t)blk * kD4;
#pragma unroll
    for (int k = 0; k < kV4; ++k) pacc4[lane + 64 * k] = acc[k];
    if (lane == 0) { pm[blk] = m; pl[blk] = l; }
}

// Pass 2: one block per b; combine np partials with global max + rescale.
__global__ __launch_bounds__(256) void
dotattn_pass2(const float* __restrict__ pacc, const float* __restrict__ pm,
              const float* __restrict__ pl, float* __restrict__ out, int np)
{
    const int b   = blockIdx.x;
    const int tid = threadIdx.x;
    __shared__ float sw[128];
    __shared__ float sM, sInv;

    if (tid == 0) {
        float M = kNegInf;
        for (int i = 0; i < np; ++i) M = fmaxf(M, pm[(size_t)b * np + i]);
        sM = M;
    }
    __syncthreads();
    const float M = sM;
    if (tid < np) sw[tid] = __expf(pm[(size_t)b * np + tid] - M);
    __syncthreads();
    if (tid == 0) {
        float ssum = 0.f;
        for (int i = 0; i < np; ++i) ssum = fmaf(sw[i], pl[(size_t)b * np + i], ssum);
        sInv = 1.f / ssum;   // >= 1 always (max chunk contributes w=1, l>=1)
    }
    __syncthreads();
    const float inv = sInv;

    // thread t owns float4 index t of the 1024-dim output
    float4 o = make_float4(0.f, 0.f, 0.f, 0.f);
    const float4* pacc4 = reinterpret_cast<const float4*>(pacc) + (size_t)b * np * kD4;
    for (int i = 0; i < np; ++i) {
        const float4 a = pacc4[(size_t)i * kD4 + tid];
        const float wi = sw[i];
        o.x = fmaf(wi, a.x, o.x);
        o.y = fmaf(wi, a.y, o.y);
        o.z = fmaf(wi, a.z, o.z);
        o.w = fmaf(wi, a.w, o.w);
    }
    o.x *= inv; o.y *= inv; o.z *= inv; o.w *= inv;
    reinterpret_cast<float4*>(out)[(size_t)b * kD4 + tid] = o;
}

extern "C" void kernel_launch(void* const* d_in, const int* in_sizes, int n_in,
                              void* d_out, int out_size, void* d_ws, size_t ws_size,
                              hipStream_t stream) {
    const float* ctx  = (const float*)d_in[0];   // [B,1,D] fp32
    const float* inp  = (const float*)d_in[1];   // [B,S,D] fp32
    const int*   mask = (const int*)d_in[2];     // [B,S] int32
    float* out = (float*)d_out;                  // [B,D] fp32

    // partials: pacc[B*np][D] + pm[B*np] + pl[B*np] in d_ws
    int np = 128;                                // s-chunks per batch (<=128)
    while (np > 1 && (size_t)kB * np * (kD + 2) * sizeof(float) > ws_size) np >>= 1;
    const int rows = kS / np;

    float* pacc = (float*)d_ws;
    float* pm   = pacc + (size_t)kB * np * kD;
    float* pl   = pm + (size_t)kB * np;

    dotattn_pass1<<<dim3(kB * np), dim3(64), 0, stream>>>(ctx, inp, mask, pacc, pm, pl, np, rows);
    dotattn_pass2<<<dim3(kB), dim3(256), 0, stream>>>(pacc, pm, pl, out, np);
}